// Round 1
// baseline (88.919 us; speedup 1.0000x reference)
//
#include <hip/hip_runtime.h>

// Problem constants (fixed shapes from setup_inputs)
constexpr int NPTS = 16384;   // points per batch
constexpr int NCTR = 2048;    // centers per batch
constexpr int NCH  = 64;      // feature channels
constexpr int KK   = 32;      // neighbors per center
constexpr int NB   = 2;       // batches
// radius^2: reference compares d2 < fp32(0.04)
#define R2 0.04f

// -------- K1: ball query. One wave per center. --------
// Reads raw float3 points (no pack kernel: saves a launch; 3 stride-12B dword
// loads per point hit the same L2 sectors as the old packed float4).
// All d2 math identical to the absmax=0-verified formulation (contract off).
// Writes out_xyz + padded idx (ws) for the channel-parallel gather kernel.
__global__ __launch_bounds__(256, 4) void query_kernel(
    const float* __restrict__ points,   // (2,16384,3)
    const float* __restrict__ centers,  // (2,2048,3)
    float* __restrict__ out_xyz,        // (2,3,2048,32)
    int* __restrict__ idx_out)          // ws: (2,2048,32)
{
#pragma clang fp contract(off)
    __shared__ int s_idx[4][KK];
    const int wave = threadIdx.x >> 6;
    const int lane = threadIdx.x & 63;
    const int cg   = blockIdx.x * 4 + wave;   // 0..4095
    const int b    = cg >> 11;
    const int g    = cg & (NCTR - 1);

    const float* pb = points + (size_t)b * NPTS * 3;
    const float* cc = centers + (size_t)cg * 3;
    const float cx = cc[0], cy = cc[1], cz = cc[2];
    const float c2 = (cx * cx + cy * cy) + cz * cz;
    int* idxs = s_idx[wave];

    // ---- chunked ballot scan: 512 pts/chunk, next chunk prefetched ----
    float curx[8], cury[8], curz[8], nxx[8], nxy[8], nxz[8];
#pragma unroll
    for (int j = 0; j < 8; ++j) {
        const int i = j * 64 + lane;
        curx[j] = pb[3 * i + 0];
        cury[j] = pb[3 * i + 1];
        curz[j] = pb[3 * i + 2];
    }
    int cnt = 0;
    for (int base = 0; base < NPTS; base += 512) {
        const int nbb = (base + 512 < NPTS) ? base + 512 : 0;
#pragma unroll
        for (int j = 0; j < 8; ++j) {
            const int i = nbb + j * 64 + lane;
            nxx[j] = pb[3 * i + 0];
            nxy[j] = pb[3 * i + 1];
            nxz[j] = pb[3 * i + 2];
        }
#pragma unroll
        for (int j = 0; j < 8; ++j) {
            const float x = curx[j], y = cury[j], z = curz[j];
            const float p2 = (x * x + y * y) + z * z;     // exact R1 formula
            const float cp = (cx * x + cy * y) + cz * z;
            const float d2 = (c2 + p2) - 2.0f * cp;
            const bool hit = d2 < R2;
            const unsigned long long m = __ballot(hit);
            if (hit) {
                const int slot = cnt + __popcll(m & ((1ull << lane) - 1ull));
                if (slot < KK) idxs[slot] = base + j * 64 + lane;
            }
            cnt += (int)__popcll(m);
        }
        if (cnt >= KK) break;                 // wave-uniform (cnt from ballot)
#pragma unroll
        for (int j = 0; j < 8; ++j) {
            curx[j] = nxx[j]; cury[j] = nxy[j]; curz[j] = nxz[j];
        }
    }
    __syncthreads();              // LDS visibility (all 4 waves reach once)

    // ---- pad + grouped_xyz + idx handoff ----
    const int cpd = cnt < KK ? cnt : KK;
    const int first = (cnt > 0) ? idxs[0] : 0;
    if (lane < KK) {
        const int id = (lane < cpd) ? idxs[lane] : first;
        idx_out[(size_t)cg * KK + lane] = id;
        const float vx = pb[3 * id + 0];
        const float vy = pb[3 * id + 1];
        const float vz = pb[3 * id + 2];
        const size_t ob = (((size_t)b * 3 + 0) * NCTR + g) * KK + lane;
        out_xyz[ob + (size_t)0 * NCTR * KK] = (vx - cx) / 0.2f;
        out_xyz[ob + (size_t)1 * NCTR * KK] = (vy - cy) / 0.2f;
        out_xyz[ob + (size_t)2 * NCTR * KK] = (vz - cz) / 0.2f;
    }
}

// -------- K2: channel-parallel feature gather. --------
// out_feat[b][c][g][k] = feats[b][c][idx[b][g][k]] : for a fixed channel the
// source is ONE 64-KB row -> stage it in LDS, then idx reads are int4-coalesced,
// gathers are LDS (random bank, ~4-way: cheap per m136), and the 64-KB output
// range per block is written as perfectly contiguous float4 streams.
// 512 blocks = (2 b) x (64 c) x (4 center-quarters), 64 KB LDS -> 2 blocks/CU,
// exactly one occupancy round.
__global__ __launch_bounds__(256, 2) void gather_kernel(
    const float* __restrict__ feats,    // (2,64,16384)
    const int* __restrict__ idx,        // (2,2048,32)
    float* __restrict__ out_feat)       // (2,64,2048,32)
{
    __shared__ float sRow[NPTS];        // 65536 B
    // XCD-chunked swizzle (bijective, 512 % 8 == 0): the 4 q-blocks of one
    // (b,c) row get consecutive work-ids within one 64-chunk -> same XCD L2.
    const int wid = ((int)blockIdx.x % 8) * 64 + (int)blockIdx.x / 8;
    const int q = wid & 3;
    const int c = (wid >> 2) & 63;
    const int b = wid >> 8;
    const int t = threadIdx.x;

    // ---- stage the channel row: 16 coalesced float4 per thread ----
    const float4* rowV = (const float4*)(feats + ((size_t)b * NCH + c) * NPTS);
    float4* sV = (float4*)sRow;
#pragma unroll
    for (int it = 0; it < 16; ++it) sV[it * 256 + t] = rowV[it * 256 + t];
    __syncthreads();

    // ---- gather + stream out: 4096 float4 per block, fully contiguous ----
    const int4* idxQ = (const int4*)(idx + ((size_t)b * NCTR + q * 512) * KK);
    float4* outQ = (float4*)(out_feat + (((size_t)b * NCH + c) * NCTR + q * 512) * KK);
#pragma unroll
    for (int it = 0; it < 16; ++it) {
        const int o = it * 256 + t;
        const int4 id4 = idxQ[o];
        float4 v;
        v.x = sRow[id4.x];
        v.y = sRow[id4.y];
        v.z = sRow[id4.z];
        v.w = sRow[id4.w];
        outQ[o] = v;
    }
}

// -------- Fallback: fused kernel (used only if ws is too small) --------
__global__ __launch_bounds__(256) void ballquery_group(
    const float* __restrict__ points, const float* __restrict__ centers,
    const float* __restrict__ feats, float* __restrict__ out_xyz,
    float* __restrict__ out_feat)
{
#pragma clang fp contract(off)
    __shared__ int   s_idx[4][KK];
    __shared__ float s_f[4][KK][65];
    const int wave = threadIdx.x >> 6, lane = threadIdx.x & 63;
    const int cg = blockIdx.x * 4 + wave;
    const int b = cg >> 11, g = cg & (NCTR - 1);
    const float* pb = points + (size_t)b * NPTS * 3;
    const float* cc = centers + (size_t)cg * 3;
    const float cx = cc[0], cy = cc[1], cz = cc[2];
    const float c2 = (cx * cx + cy * cy) + cz * cz;
    int* idxs = s_idx[wave];
    int cnt = 0;
    for (int base = 0; base < NPTS; base += 64) {
        const int i = base + lane;
        const float px = pb[i * 3 + 0], py = pb[i * 3 + 1], pz = pb[i * 3 + 2];
        const float p2 = (px * px + py * py) + pz * pz;
        const float cp = (cx * px + cy * py) + cz * pz;
        const float d2 = (c2 + p2) - 2.0f * cp;
        const bool hit = d2 < R2;
        const unsigned long long m = __ballot(hit);
        if (hit) {
            const int slot = cnt + __popcll(m & ((1ull << lane) - 1ull));
            if (slot < KK) idxs[slot] = i;
        }
        cnt += (int)__popcll(m);
        if (cnt >= KK) break;
    }
    __syncthreads();
    const int cpd = cnt < KK ? cnt : KK;
    const int first = (cnt > 0) ? idxs[0] : 0;
    if (lane < KK) idxs[lane] = (lane < cpd) ? idxs[lane] : first;
    __syncthreads();
    if (lane < KK) {
        const int id = idxs[lane];
        const float px = pb[id * 3 + 0], py = pb[id * 3 + 1], pz = pb[id * 3 + 2];
        const size_t ob = (((size_t)b * 3 + 0) * NCTR + g) * KK + lane;
        out_xyz[ob + (size_t)0 * NCTR * KK] = (px - cx) / 0.2f;
        out_xyz[ob + (size_t)1 * NCTR * KK] = (py - cy) / 0.2f;
        out_xyz[ob + (size_t)2 * NCTR * KK] = (pz - cz) / 0.2f;
    }
    float (*sf)[65] = s_f[wave];
    const float* fb = feats + (size_t)b * NCH * NPTS;
    for (int k = 0; k < KK; ++k) {
        const int id = idxs[k];
        sf[k][lane] = fb[(size_t)lane * NPTS + id];
    }
    __syncthreads();
    const int k = lane & 31, ch = lane >> 5;
    const size_t ob = ((size_t)b * NCH * NCTR + g) * KK;
#pragma unroll
    for (int cc2 = 0; cc2 < 32; ++cc2) {
        const int c = cc2 * 2 + ch;
        out_feat[ob + (size_t)c * NCTR * KK + k] = sf[k][c];
    }
}

extern "C" void kernel_launch(void* const* d_in, const int* in_sizes, int n_in,
                              void* d_out, int out_size, void* d_ws, size_t ws_size,
                              hipStream_t stream) {
    const float* points  = (const float*)d_in[0];   // (2,16384,3)
    const float* centers = (const float*)d_in[1];   // (2,2048,3)
    const float* feats   = (const float*)d_in[2];   // (2,64,16384)

    float* out      = (float*)d_out;
    float* out_xyz  = out;                                    // (2,3,2048,32)
    float* out_feat = out + (size_t)NB * 3 * NCTR * KK;       // (2,64,2048,32)

    const size_t idxBytes = (size_t)NB * NCTR * KK * sizeof(int);   // 512 KB

    if (ws_size >= idxBytes) {
        int* idx_ws = (int*)d_ws;
        // 4096 centers, 4 per block (one wave each)
        query_kernel<<<(NB * NCTR) / 4, 256, 0, stream>>>(
            points, centers, out_xyz, idx_ws);
        // (2 b) x (64 c) x (4 quarters) = 512 blocks
        gather_kernel<<<NB * NCH * 4, 256, 0, stream>>>(
            feats, idx_ws, out_feat);
    } else {
        ballquery_group<<<(NB * NCTR) / 4, 256, 0, stream>>>(
            points, centers, feats, out_xyz, out_feat);
    }
}